// Round 4
// baseline (136.956 us; speedup 1.0000x reference)
//
#include <hip/hip_runtime.h>
#include <hip/hip_bf16.h>

// BilinearPooling: out[b, i*2048+j] = xp[b,i]*yp[b,j] / max(||xp_b||*||yp_b||, eps)
// where xp = x @ W^T, yp = y @ W^T.  B=32, D_IN=1024, D_OUT=2048, fp32.
// ||outer(u,v)||_F = ||u||*||v||  ->  never materialize z before normalizing.
// Roofline: 512 MiB of pure streaming writes @ ~6.7 TB/s (measured fill rate) ~= 80 us.
// R3 lesson: per-block contiguous 256KB regions gave only ~5.4 TB/s; this round the
// writer walks the output in fill-style lockstep grid-stride (8 MiB window / iter).

#define BROWS 64       // stacked rows: 32 x-rows then 32 y-rows
#define DIN   1024
#define DOUT  2048
#define OTILE 64
#define LDA   132      // padded LDS leading dim (floats)
#define EPS_N 1e-12f

// ---------------- Kernel 1: partial GEMM  proj_partial[ks][r][o] ----------------
template <int KS>
__global__ __launch_bounds__(256) void gemm_partial_k(
    const float* __restrict__ x, const float* __restrict__ y,
    const float* __restrict__ W, float* __restrict__ part)
{
    constexpr int KCHUNK = DIN / KS;
    constexpr int NSTAGE = KCHUNK / 128;

    const int o0 = blockIdx.x * OTILE;
    const int ks = blockIdx.y;
    const int t  = threadIdx.x;

    __shared__ float As[BROWS * LDA];
    __shared__ float Bs[OTILE * LDA];

    const int tr = t >> 4;
    const int tc = t & 15;

    float acc[4][4];
#pragma unroll
    for (int a = 0; a < 4; ++a)
#pragma unroll
        for (int b = 0; b < 4; ++b) acc[a][b] = 0.f;

    for (int st = 0; st < NSTAGE; ++st) {
        const int k0 = ks * KCHUNK + st * 128;
        if (st) __syncthreads();
#pragma unroll
        for (int i = 0; i < 8; ++i) {
            int li = t + i * 256;
            int r  = li >> 5;
            int c4 = li & 31;
            const float* src =
                (r < 32 ? x + (size_t)r * DIN : y + (size_t)(r - 32) * DIN)
                + k0 + c4 * 4;
            *(float4*)&As[r * LDA + c4 * 4] = *(const float4*)src;
        }
#pragma unroll
        for (int i = 0; i < 8; ++i) {
            int li = t + i * 256;
            int r  = li >> 5;
            int c4 = li & 31;
            *(float4*)&Bs[r * LDA + c4 * 4] =
                *(const float4*)(W + (size_t)(o0 + r) * DIN + k0 + c4 * 4);
        }
        __syncthreads();

#pragma unroll 8
        for (int k4 = 0; k4 < 32; ++k4) {
            const int k = k4 * 4;
            float4 av[4], bv[4];
#pragma unroll
            for (int rr = 0; rr < 4; ++rr)
                av[rr] = *(float4*)&As[(tr + 16 * rr) * LDA + k];
#pragma unroll
            for (int cc = 0; cc < 4; ++cc)
                bv[cc] = *(float4*)&Bs[(tc + 16 * cc) * LDA + k];
#pragma unroll
            for (int rr = 0; rr < 4; ++rr)
#pragma unroll
                for (int cc = 0; cc < 4; ++cc) {
                    acc[rr][cc] = fmaf(av[rr].x, bv[cc].x, acc[rr][cc]);
                    acc[rr][cc] = fmaf(av[rr].y, bv[cc].y, acc[rr][cc]);
                    acc[rr][cc] = fmaf(av[rr].z, bv[cc].z, acc[rr][cc]);
                    acc[rr][cc] = fmaf(av[rr].w, bv[cc].w, acc[rr][cc]);
                }
        }
    }

#pragma unroll
    for (int rr = 0; rr < 4; ++rr) {
        const int r = tr + 16 * rr;
#pragma unroll
        for (int cc = 0; cc < 4; ++cc) {
            const int o = o0 + tc + 16 * cc;
            part[((size_t)(ks * BROWS + r)) * DOUT + o] = acc[rr][cc];
        }
    }
}

// ---------------- Kernel 2: reduce partials + row norms ----------------
template <int KS>
__global__ __launch_bounds__(256) void reduce_rows_k(
    const float* __restrict__ part, float* __restrict__ proj,
    float* __restrict__ norms)
{
    const int r = blockIdx.x;
    const int t = threadIdx.x;
    float ss = 0.f;
#pragma unroll
    for (int it = 0; it < 2; ++it) {
        const int j4 = t + it * 256;
        float4 s = make_float4(0.f, 0.f, 0.f, 0.f);
#pragma unroll
        for (int ks = 0; ks < KS; ++ks) {
            float4 v = *(const float4*)&part[((size_t)(ks * BROWS + r)) * DOUT + j4 * 4];
            s.x += v.x; s.y += v.y; s.z += v.z; s.w += v.w;
        }
        *(float4*)&proj[(size_t)r * DOUT + j4 * 4] = s;
        ss += s.x * s.x + s.y * s.y + s.z * s.z + s.w * s.w;
    }
#pragma unroll
    for (int m = 32; m >= 1; m >>= 1) ss += __shfl_xor(ss, m, 64);
    __shared__ float red[4];
    const int lane = t & 63, wv = t >> 6;
    if (lane == 0) red[wv] = ss;
    __syncthreads();
    if (t == 0) norms[r] = sqrtf(red[0] + red[1] + red[2] + red[3]);
}

// ---------------- Kernel 3: lockstep grid-stride streaming write ----------------
// Global float4 index per iteration: g4 = blk*256 + t + it * 2^19   (it = 0..63)
// Decode (all power-of-two): b = it>>1;  i = (blk>>1) + (it&1)*1024;
//                            j = (blk&1)*1024 + 4t
// => all-scalar addressing; one contiguous 8 MiB window per iteration, like fill.
__global__ __launch_bounds__(256) void outer_write_stream(
    const float* __restrict__ proj, const float* __restrict__ norms,
    float* __restrict__ out)
{
    const int blk = blockIdx.x;          // 0..2047
    const int t   = threadIdx.x;         // 0..255
    const int j   = ((blk & 1) << 10) + t * 4;
    const int i0  = blk >> 1;            // 0..1023

    float4* outp = (float4*)out + ((size_t)blk * 256 + t);
    const size_t step = (size_t)1 << 19; // float4 stride per iteration = 8 MiB

#pragma unroll 4
    for (int b = 0; b < 32; ++b) {
        const float s  = 1.0f / fmaxf(norms[b] * norms[32 + b], EPS_N);
        const float4 yv = *(const float4*)&proj[(size_t)(32 + b) * DOUT + j];
        const float y0 = yv.x * s, y1 = yv.y * s, y2 = yv.z * s, y3 = yv.w * s;
#pragma unroll
        for (int ih = 0; ih < 2; ++ih) {
            const float xv = proj[(size_t)b * DOUT + i0 + (ih << 10)];
            const float4 o = make_float4(xv * y0, xv * y1, xv * y2, xv * y3);
            *outp = o;
            outp += step;
        }
    }
}

// ---------------- launch ----------------
template <int KS>
static void run_pipeline(const float* x, const float* y, const float* W,
                         float* out, float* ws, hipStream_t stream)
{
    float* part  = ws;
    float* proj  = part + (size_t)KS * BROWS * DOUT;
    float* norms = proj + (size_t)BROWS * DOUT;
    gemm_partial_k<KS><<<dim3(DOUT / OTILE, KS), 256, 0, stream>>>(x, y, W, part);
    reduce_rows_k<KS><<<BROWS, 256, 0, stream>>>(part, proj, norms);
    outer_write_stream<<<2048, 256, 0, stream>>>(proj, norms, out);
}

extern "C" void kernel_launch(void* const* d_in, const int* in_sizes, int n_in,
                              void* d_out, int out_size, void* d_ws, size_t ws_size,
                              hipStream_t stream)
{
    const float* x = (const float*)d_in[0];
    const float* y = (const float*)d_in[1];
    const float* W = (const float*)d_in[2];
    float* out = (float*)d_out;
    float* ws  = (float*)d_ws;

    const size_t need8 = ((size_t)8 * BROWS * DOUT + (size_t)BROWS * DOUT + 64) * sizeof(float);
    const size_t need4 = ((size_t)4 * BROWS * DOUT + (size_t)BROWS * DOUT + 64) * sizeof(float);

    if (ws_size >= need8)
        run_pipeline<8>(x, y, W, out, ws, stream);
    else if (ws_size >= need4)
        run_pipeline<4>(x, y, W, out, ws, stream);
    else
        run_pipeline<1>(x, y, W, out, ws, stream);
}

// Round 5
// 110.664 us; speedup vs baseline: 1.2376x; 1.2376x over previous
//
#include <hip/hip_runtime.h>
#include <hip/hip_bf16.h>

// BilinearPooling: out[b, i*2048+j] = xp[b,i]*yp[b,j] / max(||xp_b||*||yp_b||, eps)
// where xp = x @ W^T, yp = y @ W^T.  B=32, D_IN=1024, D_OUT=2048, fp32.
// ||outer(u,v)||_F = ||u||*||v||  ->  never materialize z before normalizing.
// Roofline: 512 MiB streaming writes @ ~6.7 TB/s (measured fill rate) ~= 80 us.
// R4 lesson: per-wave store contiguity is what matters. 1KB chunks at 8MiB stride
// (R4) = DRAM row-thrash, 137us. 1KB @ 4KB stride (R1/R3) = 110us. This round:
// each wave writes a fully sequential 64KB run.

#define BROWS 64       // stacked rows: 32 x-rows then 32 y-rows
#define DIN   1024
#define DOUT  2048
#define OTILE 64
#define LDA   132      // padded LDS leading dim (floats)
#define EPS_N 1e-12f

// ---------------- Kernel 1: partial GEMM  proj_partial[ks][r][o] ----------------
template <int KS>
__global__ __launch_bounds__(256) void gemm_partial_k(
    const float* __restrict__ x, const float* __restrict__ y,
    const float* __restrict__ W, float* __restrict__ part)
{
    constexpr int KCHUNK = DIN / KS;
    constexpr int NSTAGE = KCHUNK / 128;

    const int o0 = blockIdx.x * OTILE;
    const int ks = blockIdx.y;
    const int t  = threadIdx.x;

    __shared__ float As[BROWS * LDA];
    __shared__ float Bs[OTILE * LDA];

    const int tr = t >> 4;
    const int tc = t & 15;

    float acc[4][4];
#pragma unroll
    for (int a = 0; a < 4; ++a)
#pragma unroll
        for (int b = 0; b < 4; ++b) acc[a][b] = 0.f;

    for (int st = 0; st < NSTAGE; ++st) {
        const int k0 = ks * KCHUNK + st * 128;
        if (st) __syncthreads();
#pragma unroll
        for (int i = 0; i < 8; ++i) {
            int li = t + i * 256;
            int r  = li >> 5;
            int c4 = li & 31;
            const float* src =
                (r < 32 ? x + (size_t)r * DIN : y + (size_t)(r - 32) * DIN)
                + k0 + c4 * 4;
            *(float4*)&As[r * LDA + c4 * 4] = *(const float4*)src;
        }
#pragma unroll
        for (int i = 0; i < 8; ++i) {
            int li = t + i * 256;
            int r  = li >> 5;
            int c4 = li & 31;
            *(float4*)&Bs[r * LDA + c4 * 4] =
                *(const float4*)(W + (size_t)(o0 + r) * DIN + k0 + c4 * 4);
        }
        __syncthreads();

#pragma unroll 8
        for (int k4 = 0; k4 < 32; ++k4) {
            const int k = k4 * 4;
            float4 av[4], bv[4];
#pragma unroll
            for (int rr = 0; rr < 4; ++rr)
                av[rr] = *(float4*)&As[(tr + 16 * rr) * LDA + k];
#pragma unroll
            for (int cc = 0; cc < 4; ++cc)
                bv[cc] = *(float4*)&Bs[(tc + 16 * cc) * LDA + k];
#pragma unroll
            for (int rr = 0; rr < 4; ++rr)
#pragma unroll
                for (int cc = 0; cc < 4; ++cc) {
                    acc[rr][cc] = fmaf(av[rr].x, bv[cc].x, acc[rr][cc]);
                    acc[rr][cc] = fmaf(av[rr].y, bv[cc].y, acc[rr][cc]);
                    acc[rr][cc] = fmaf(av[rr].z, bv[cc].z, acc[rr][cc]);
                    acc[rr][cc] = fmaf(av[rr].w, bv[cc].w, acc[rr][cc]);
                }
        }
    }

#pragma unroll
    for (int rr = 0; rr < 4; ++rr) {
        const int r = tr + 16 * rr;
#pragma unroll
        for (int cc = 0; cc < 4; ++cc) {
            const int o = o0 + tc + 16 * cc;
            part[((size_t)(ks * BROWS + r)) * DOUT + o] = acc[rr][cc];
        }
    }
}

// ---------------- Kernel 2: reduce partials + row norms ----------------
template <int KS>
__global__ __launch_bounds__(256) void reduce_rows_k(
    const float* __restrict__ part, float* __restrict__ proj,
    float* __restrict__ norms)
{
    const int r = blockIdx.x;
    const int t = threadIdx.x;
    float ss = 0.f;
#pragma unroll
    for (int it = 0; it < 2; ++it) {
        const int j4 = t + it * 256;
        float4 s = make_float4(0.f, 0.f, 0.f, 0.f);
#pragma unroll
        for (int ks = 0; ks < KS; ++ks) {
            float4 v = *(const float4*)&part[((size_t)(ks * BROWS + r)) * DOUT + j4 * 4];
            s.x += v.x; s.y += v.y; s.z += v.z; s.w += v.w;
        }
        *(float4*)&proj[(size_t)r * DOUT + j4 * 4] = s;
        ss += s.x * s.x + s.y * s.y + s.z * s.z + s.w * s.w;
    }
#pragma unroll
    for (int m = 32; m >= 1; m >>= 1) ss += __shfl_xor(ss, m, 64);
    __shared__ float red[4];
    const int lane = t & 63, wv = t >> 6;
    if (lane == 0) red[wv] = ss;
    __syncthreads();
    if (t == 0) norms[r] = sqrtf(red[0] + red[1] + red[2] + red[3]);
}

// ---------------- Kernel 3: per-wave-sequential streaming write ----------------
// Block = (b, 32 rows). Wave w owns rows i0+8w .. i0+8w+7 = contiguous 64 KB.
// Store order (r, s): consecutive wave stores advance exactly +1 KB -> each wave
// walks a sequential 64 KB run. y-row in 8 float4 regs/lane (scale folded).
__global__ __launch_bounds__(256) void outer_write_v3(
    const float* __restrict__ proj, const float* __restrict__ norms,
    float* __restrict__ out)
{
    const int blk = blockIdx.x;        // 0..2047
    const int b   = blk >> 6;          // 0..31
    const int i0  = (blk & 63) << 5;   // row tile of 32
    const int t   = threadIdx.x;
    const int w   = t >> 6;            // wave 0..3
    const int l   = t & 63;

    const float s = 1.0f / fmaxf(norms[b] * norms[32 + b], EPS_N);

    // lane l covers columns sseg*256 + 4l .. +3, sseg = 0..7
    const float* yrow = proj + (size_t)(32 + b) * DOUT;
    float4 y4[8];
#pragma unroll
    for (int sseg = 0; sseg < 8; ++sseg) {
        float4 v = *(const float4*)&yrow[sseg * 256 + l * 4];
        y4[sseg] = make_float4(v.x * s, v.y * s, v.z * s, v.w * s);
    }

    const float* xrow = proj + (size_t)b * DOUT + i0 + w * 8;
    float4* outp = (float4*)out
        + ((size_t)b * DOUT + i0 + w * 8) * (DOUT / 4) + l;

#pragma unroll
    for (int r = 0; r < 8; ++r) {
        const float xv = xrow[r];
#pragma unroll
        for (int sseg = 0; sseg < 8; ++sseg) {
            float4 o = make_float4(xv * y4[sseg].x, xv * y4[sseg].y,
                                   xv * y4[sseg].z, xv * y4[sseg].w);
            outp[(size_t)r * (DOUT / 4) + sseg * 64] = o;
        }
    }
}

// ---------------- launch ----------------
template <int KS>
static void run_pipeline(const float* x, const float* y, const float* W,
                         float* out, float* ws, hipStream_t stream)
{
    float* part  = ws;
    float* proj  = part + (size_t)KS * BROWS * DOUT;
    float* norms = proj + (size_t)BROWS * DOUT;
    gemm_partial_k<KS><<<dim3(DOUT / OTILE, KS), 256, 0, stream>>>(x, y, W, part);
    reduce_rows_k<KS><<<BROWS, 256, 0, stream>>>(part, proj, norms);
    outer_write_v3<<<2048, 256, 0, stream>>>(proj, norms, out);
}

extern "C" void kernel_launch(void* const* d_in, const int* in_sizes, int n_in,
                              void* d_out, int out_size, void* d_ws, size_t ws_size,
                              hipStream_t stream)
{
    const float* x = (const float*)d_in[0];
    const float* y = (const float*)d_in[1];
    const float* W = (const float*)d_in[2];
    float* out = (float*)d_out;
    float* ws  = (float*)d_ws;

    const size_t need8 = ((size_t)8 * BROWS * DOUT + (size_t)BROWS * DOUT + 64) * sizeof(float);
    const size_t need4 = ((size_t)4 * BROWS * DOUT + (size_t)BROWS * DOUT + 64) * sizeof(float);

    if (ws_size >= need8)
        run_pipeline<8>(x, y, W, out, ws, stream);
    else if (ws_size >= need4)
        run_pipeline<4>(x, y, W, out, ws, stream);
    else
        run_pipeline<1>(x, y, W, out, ws, stream);
}